// Round 10
// baseline (1027.787 us; speedup 1.0000x reference)
//
#include <hip/hip_runtime.h>

#define NN 50000
#define NE 800000
#define BINS 98      // bins of 512 nodes per branch
#define CAP 12288    // per-bin capacity (u32 records / ushort csr entries)
#define EPB 4096     // edges per phase-1 block
#define P1B ((NE + EPB - 1) / EPB)  // 196 blocks per branch

// class-swept gather geometry
#define CH 1563              // node-chunks per class (32 nodes each)
#define CLS1 24              // layer1: 3 branches x 8 colgroups(32 cols of 256)
#define T1 (CLS1 * CH)       // 37512 wave-tasks
#define TPX1 (T1 / 8)        // 4689 per XCD
#define CLS2 12              // layer2: 3 branches x 4 colgroups(32 cols of 128)
#define T2 (CLS2 * CH)       // 18756 wave-tasks

typedef __attribute__((ext_vector_type(8))) short short8;
typedef __attribute__((ext_vector_type(4))) float f32x4;
typedef _Float16 half8 __attribute__((ext_vector_type(8)));

__device__ __forceinline__ ushort f2bf(float f) {
    unsigned u = __float_as_uint(f);
    unsigned r = (u + 0x7fffu + ((u >> 16) & 1u)) >> 16;
    return (ushort)r;
}
__device__ __forceinline__ float bf2f(ushort h) {
    return __uint_as_float(((unsigned)h) << 16);
}
__device__ __forceinline__ ushort f2h(float f) {
    _Float16 h = (_Float16)f;
    return __builtin_bit_cast(ushort, h);
}
__device__ __forceinline__ float h2f(ushort u) {
    return (float)__builtin_bit_cast(_Float16, u);
}

// ---------------- phase 1: bin edges by dst>>9, coalesced line-exclusive flush ----

__global__ __launch_bounds__(256) void k_bin(const int* __restrict__ e0,
                                             const int* __restrict__ e1,
                                             const int* __restrict__ e2,
                                             int* __restrict__ g_cur,
                                             unsigned* __restrict__ g_bins) {
    const int br = blockIdx.x / P1B;
    const int cb = blockIdx.x % P1B;
    const int* ep = (br == 0 ? e0 : br == 1 ? e1 : e2);
    const int tid = threadIdx.x;
    const int e_base = cb * EPB;

    __shared__ int s_cnt[BINS];
    __shared__ int s_start[BINS];
    __shared__ int s_cur[BINS];
    __shared__ int s_gb[BINS];
    __shared__ unsigned s_stage[EPB];

    if (tid < BINS) s_cnt[tid] = 0;
    __syncthreads();

    int4 s4[4], d4[4];
    bool valid[4];
#pragma unroll
    for (int i = 0; i < 4; ++i) {
        int idx = e_base + i * 1024 + tid * 4;
        valid[i] = (idx < NE);  // idx%4==0, NE%4==0 -> full int4 valid
        if (valid[i]) {
            s4[i] = *(const int4*)&ep[idx];
            d4[i] = *(const int4*)&ep[NE + idx];
            atomicAdd(&s_cnt[d4[i].x >> 9], 1);
            atomicAdd(&s_cnt[d4[i].y >> 9], 1);
            atomicAdd(&s_cnt[d4[i].z >> 9], 1);
            atomicAdd(&s_cnt[d4[i].w >> 9], 1);
        }
    }
    __syncthreads();
    if (tid == 0) {
        int run = 0;
        for (int b = 0; b < BINS; ++b) {
            s_start[b] = run;
            run += s_cnt[b];
        }
    }
    __syncthreads();
    if (tid < BINS) {
        s_cur[tid] = s_start[tid];
        int c = s_cnt[tid];
        int pc = (c + 15) & ~15;  // 64B-aligned reservation
        s_gb[tid] = (c > 0) ? atomicAdd(&g_cur[br * BINS + tid], pc) : 0;
    }
    __syncthreads();

#pragma unroll
    for (int i = 0; i < 4; ++i) {
        if (valid[i]) {
            int ss[4] = {s4[i].x, s4[i].y, s4[i].z, s4[i].w};
            int dd[4] = {d4[i].x, d4[i].y, d4[i].z, d4[i].w};
#pragma unroll
            for (int q = 0; q < 4; ++q) {
                int bin = dd[q] >> 9;
                int pos = atomicAdd(&s_cur[bin], 1);
                s_stage[pos] = ((unsigned)(dd[q] & 511) << 16) | (unsigned)ss[q];
            }
        }
    }
    __syncthreads();

    for (int b = 0; b < BINS; ++b) {
        int c = s_cnt[b];
        if (c == 0) continue;
        int st = s_start[b];
        int gb = s_gb[b];
        int pc = (c + 15) & ~15;
        if (gb + pc > CAP) pc = (gb < CAP) ? (CAP - gb) : 0;  // overflow guard
        size_t obase = (size_t)(br * BINS + b) * CAP + gb;
        for (int j = tid; j < pc; j += 256)
            g_bins[obase + j] = (j < c) ? s_stage[st + j] : 0x80000000u;
    }
}

// ---------------- phase 2: per-bin CSR build with LDS atomics ----------------

__device__ __forceinline__ int wave_incl_scan(int v, int lane) {
#pragma unroll
    for (int d = 1; d < 64; d <<= 1) {
        int u = __shfl_up(v, d);
        if (lane >= d) v += u;
    }
    return v;
}

__global__ __launch_bounds__(256) void k_build(const unsigned* __restrict__ g_bins,
                                               const int* __restrict__ g_cur,
                                               ushort* __restrict__ g_csr,
                                               int* __restrict__ seg3,
                                               int* __restrict__ cnt3,
                                               float* __restrict__ dinv3) {
    const int bid = blockIdx.x;  // branch*BINS + bin
    const int br = bid / BINS;
    const int b2 = bid % BINS;
    const size_t base = (size_t)bid * CAP;
    const int node0 = b2 << 9;
    const int tid = threadIdx.x;

    __shared__ int s_cnt[512];
    __shared__ int s_off[512];
    __shared__ int s_wsum[4];

    s_cnt[tid] = 0;
    s_cnt[tid + 256] = 0;
    __syncthreads();

    const int total = min(g_cur[bid], CAP);
    for (int j = tid; j < total; j += 256) {
        unsigned p = g_bins[base + j];
        if (!(p & 0x80000000u)) atomicAdd(&s_cnt[(p >> 16) & 0x1FF], 1);
    }
    __syncthreads();

    // exclusive scan of 512 counts (pairs per thread + wave scan)
    const int lane = tid & 63, w = tid >> 6;
    int c0 = s_cnt[2 * tid], c1 = s_cnt[2 * tid + 1];
    int c2 = c0 + c1;
    int incl = wave_incl_scan(c2, lane);
    if (lane == 63) s_wsum[w] = incl;
    __syncthreads();
    int wpre = 0;
    for (int i = 0; i < w; ++i) wpre += s_wsum[i];
    int ex = wpre + incl - c2;
    s_off[2 * tid] = ex;
    s_off[2 * tid + 1] = ex + c0;

#pragma unroll
    for (int q = 0; q < 2; ++q) {
        int local = 2 * tid + q;
        int node = node0 + local;
        if (node < NN) {
            int g = br * NN + node;
            int c = (q == 0) ? c0 : c1;
            seg3[g] = (int)base + s_off[local];
            cnt3[g] = c;
            dinv3[g] = rsqrtf((float)(c + 1));
        }
    }
    __syncthreads();
    // cursors
    s_cnt[2 * tid] = s_off[2 * tid];
    s_cnt[2 * tid + 1] = s_off[2 * tid + 1];
    __syncthreads();

    for (int j = tid; j < total; j += 256) {
        unsigned p = g_bins[base + j];
        if (!(p & 0x80000000u)) {
            int loc = (p >> 16) & 0x1FF;
            int pos = atomicAdd(&s_cnt[loc], 1);
            g_csr[base + pos] = (ushort)(p & 0xFFFFu);
        }
    }
}

// ---------------- conversions ----------------

__global__ __launch_bounds__(256) void k_conv_x(const float* __restrict__ x,
                                                ushort* __restrict__ xp) {
    const int wid = threadIdx.x >> 6, lane = threadIdx.x & 63;
    const int row = blockIdx.x * 4 + wid;
    if (row >= NN) return;
    float4 v = *(const float4*)&x[(size_t)row * 256 + lane * 4];
    ushort4 hi, lo;
    hi.x = f2bf(v.x); lo.x = f2bf(v.x - bf2f(hi.x));
    hi.y = f2bf(v.y); lo.y = f2bf(v.y - bf2f(hi.y));
    hi.z = f2bf(v.z); lo.z = f2bf(v.z - bf2f(hi.z));
    hi.w = f2bf(v.w); lo.w = f2bf(v.w - bf2f(hi.w));
    *(ushort4*)&xp[(size_t)row * 512 + lane * 4] = hi;
    *(ushort4*)&xp[(size_t)row * 512 + 256 + lane * 4] = lo;
}

__global__ __launch_bounds__(256) void k_conv_w1(const float* __restrict__ w0,
                                                 const float* __restrict__ w1,
                                                 const float* __restrict__ w2,
                                                 ushort* __restrict__ BT1all) {
    int idx = blockIdx.x * 256 + threadIdx.x;  // 3 * 65536
    int b = idx >> 16, r = idx & 65535;
    int k = r >> 8, n = r & 255;
    const float* W = (b == 0 ? w0 : b == 1 ? w1 : w2);
    float w = W[r];
    ushort hi = f2bf(w);
    ushort lo = f2bf(w - bf2f(hi));
    ushort* row = BT1all + (size_t)b * 196608 + (size_t)n * 768;
    row[k] = hi;
    row[256 + k] = hi;
    row[512 + k] = lo;
}

__global__ __launch_bounds__(256) void k_conv_w2(const float* __restrict__ w0,
                                                 const float* __restrict__ w1,
                                                 const float* __restrict__ w2,
                                                 ushort* __restrict__ BT2all) {
    int idx = blockIdx.x * 256 + threadIdx.x;  // 3 * 32768
    int b = idx >> 15, r = idx & 32767;
    int k = r >> 7, n = r & 127;
    const float* W = (b == 0 ? w0 : b == 1 ? w1 : w2);
    BT2all[(size_t)b * 32768 + (size_t)n * 256 + k] = f2h(W[r]);
}

// ---------------- MFMA GEMM: 2-phase double-buffered pipeline ----------------

template <int BM, int BN, int N, int KK, int AK, bool HALF, bool XSWZ>
__global__ __launch_bounds__((BM / 64) * (BN / 64) * 64) void k_gemm(
    const ushort* __restrict__ A, size_t aBatch,
    const ushort* __restrict__ BTall, int btBatch,
    const float* __restrict__ dinv3, ushort* __restrict__ Call, size_t cBatch) {
    constexpr int WGN = BN / 64, NW = (BM / 64) * WGN;
    constexpr int BK = 32;
    constexpr int MT = (NN + BM - 1) / BM, NT = N / BN, GB = MT * NT;
    constexpr int NSTEP = KK / BK;
    __shared__ ushort sA[2][BM * BK];
    __shared__ ushort sB[2][BN * BK];
    int kb, bid;
    if constexpr (XSWZ) {
        int q = blockIdx.x >> 3, r = blockIdx.x & 7;
        bid = (q / 3) * 8 + r;   // M-tile
        kb = q % 3;              // branch
        if (bid >= GB) return;
    } else {
        kb = blockIdx.x / GB;
        bid = blockIdx.x % GB;
    }
    const ushort* Ab = A + (size_t)kb * aBatch;
    const ushort* BT = BTall + (size_t)kb * btBatch;
    const float* dinv = dinv3 + (size_t)kb * NN;
    ushort* C = Call + (size_t)kb * cBatch;
    const int t = threadIdx.x, lane = t & 63, wid = t >> 6;
    const int wm = (wid / WGN) * 64, wn = (wid % WGN) * 64;
    const int bm = (bid / NT) * BM;
    const int bn = (bid % NT) * BN;

    f32x4 zero = {0.f, 0.f, 0.f, 0.f};
    f32x4 acc[4][4];
#pragma unroll
    for (int m = 0; m < 4; ++m)
#pragma unroll
        for (int n = 0; n < 4; ++n) acc[m][n] = zero;

    constexpr int A_ISS = (BM * BK * 2) / (NW * 1024);
    constexpr int B_ISS = (BN * BK * 2) / (NW * 1024);

    auto stage = [&](int buf, int kt) {
        const int akt = (kt >= AK) ? kt - AK : kt;  // A hi-block reuse
#pragma unroll
        for (int i = 0; i < A_ISS; ++i) {
            int off = (wid + i * NW) << 10;
            int la = off + lane * 16;
            int row = la >> 6;
            int slot = (la >> 4) & 3;
            int scol = (slot ^ (row & 3)) << 4;
            int grow = bm + row;
            if (grow > NN - 1) grow = NN - 1;
            const char* ga = (const char*)Ab + (size_t)grow * (AK * 2) + akt * 2 + scol;
            __builtin_amdgcn_global_load_lds(
                (__attribute__((address_space(1))) const void*)ga,
                (__attribute__((address_space(3))) void*)((char*)sA[buf] + off), 16, 0, 0);
        }
#pragma unroll
        for (int i = 0; i < B_ISS; ++i) {
            int off = (wid + i * NW) << 10;
            int la = off + lane * 16;
            int row = la >> 6;
            int slot = (la >> 4) & 3;
            int scol = (slot ^ (row & 3)) << 4;
            const char* ga = (const char*)BT + (size_t)(bn + row) * (KK * 2) + kt * 2 + scol;
            __builtin_amdgcn_global_load_lds(
                (__attribute__((address_space(1))) const void*)ga,
                (__attribute__((address_space(3))) void*)((char*)sB[buf] + off), 16, 0, 0);
        }
    };

    stage(0, 0);
    __syncthreads();  // drain prologue loads

    int cur = 0;
    for (int ts = 0; ts < NSTEP; ++ts) {
        if (ts + 1 < NSTEP) stage(cur ^ 1, (ts + 1) * BK);  // overlap with MFMA

        const int s = lane >> 4;
        const int r0 = lane & 15;
        short8 af[4], bf[4];
#pragma unroll
        for (int m = 0; m < 4; ++m) {
            int row = wm + m * 16 + r0;
            af[m] = *(const short8*)((const char*)sA[cur] + row * 64 + ((s ^ (row & 3)) << 4));
        }
#pragma unroll
        for (int n = 0; n < 4; ++n) {
            int row = wn + n * 16 + r0;
            bf[n] = *(const short8*)((const char*)sB[cur] + row * 64 + ((s ^ (row & 3)) << 4));
        }
#pragma unroll
        for (int m = 0; m < 4; ++m)
#pragma unroll
            for (int n = 0; n < 4; ++n) {
                if constexpr (HALF)
                    acc[m][n] = __builtin_amdgcn_mfma_f32_16x16x32_f16(
                        __builtin_bit_cast(half8, af[m]), __builtin_bit_cast(half8, bf[n]),
                        acc[m][n], 0, 0, 0);
                else
                    acc[m][n] = __builtin_amdgcn_mfma_f32_16x16x32_bf16(af[m], bf[n],
                                                                        acc[m][n], 0, 0, 0);
            }
        __syncthreads();  // drains vmcnt(0): next tile staged & visible
        cur ^= 1;
    }

    const int cr0 = (lane >> 4) * 4;
    const int cc = lane & 15;
#pragma unroll
    for (int m = 0; m < 4; ++m) {
#pragma unroll
        for (int r = 0; r < 4; ++r) {
            int row = bm + wm + m * 16 + cr0 + r;
            if (row < NN) {
                float dv = dinv[row];
#pragma unroll
                for (int n = 0; n < 4; ++n)
                    C[(size_t)row * N + bn + wn + n * 16 + cc] = f2h(acc[m][n][r] * dv);
            }
        }
    }
}

// ---------------- layer-1 aggregation: class-swept column-split gather ------
// 24 classes = (branch, 32-col group); class working set = 50000 x 64B = 3.2MB
// < 4MB XCD L2. blockIdx%8 -> XCD; XCD x runs classes {x, x+8, x+16}
// sequentially -> near-compulsory fetch. Wave = (class, 32-node chunk);
// half-waves process alternating msgs; 1 col/lane, f32 reg accumulator.

__global__ __launch_bounds__(256) void k_agg1(const ushort* __restrict__ hs16all,
                                              const int* __restrict__ seg3,
                                              const int* __restrict__ cnt3,
                                              const ushort* __restrict__ g_csr,
                                              const float* __restrict__ dinv3,
                                              const float* __restrict__ b1a,
                                              const float* __restrict__ b1b,
                                              const float* __restrict__ b1c,
                                              ushort* __restrict__ h1all) {
    const int x = blockIdx.x & 7, jb = blockIdx.x >> 3;
    const int w = threadIdx.x >> 6, lane = threadIdx.x & 63;
    const int tj = jb * 4 + w;
    if (tj >= TPX1) return;
    const int t = x * TPX1 + tj;
    const int cls = t / CH, chunk = t % CH;
    const int br = cls >> 3, cg = cls & 7;
    const int half = lane >> 5, l32 = lane & 31;
    const int col = cg * 32 + l32;
    const ushort* hs = hs16all + (size_t)br * NN * 256 + col;
    const float* bias = (br == 0 ? b1a : br == 1 ? b1b : b1c);
    const float bcol = bias[col];
    const int n1 = min(chunk * 32 + 32, NN);

    for (int node = chunk * 32; node < n1; ++node) {
        const int g = br * NN + node;
        const ushort* csr = g_csr + seg3[g];
        const int len = cnt3[g] + 1;
        float acc = 0.f;
        int i = half;
        for (; i + 6 < len; i += 8) {
            int s0 = (i == 0) ? node : (int)csr[i - 1];
            int s1 = (int)csr[i + 1];
            int s2 = (int)csr[i + 3];
            int s3 = (int)csr[i + 5];
            float v0 = h2f(hs[(size_t)s0 * 256]);
            float v1 = h2f(hs[(size_t)s1 * 256]);
            float v2 = h2f(hs[(size_t)s2 * 256]);
            float v3 = h2f(hs[(size_t)s3 * 256]);
            acc += (v0 + v1) + (v2 + v3);
        }
        for (; i < len; i += 2) {
            int s = (i == 0) ? node : (int)csr[i - 1];
            acc += h2f(hs[(size_t)s * 256]);
        }
        acc += __shfl_xor(acc, 32);
        if (half == 0) {
            float r = fmaxf(dinv3[g] * acc + bcol, 0.f);
            h1all[(size_t)g * 256 + col] = f2h(r);
        }
    }
}

// ---------------- layer-2 aggregation: class-swept, writes feats fp16 -------
// 12 classes = (branch, 32-col group of 128). feats layout [node][branch][128].

__global__ __launch_bounds__(256) void k_feat(const ushort* __restrict__ hs2all,
                                              const int* __restrict__ seg3,
                                              const int* __restrict__ cnt3,
                                              const ushort* __restrict__ g_csr,
                                              const float* __restrict__ dinv3,
                                              const float* __restrict__ b2a,
                                              const float* __restrict__ b2b,
                                              const float* __restrict__ b2c,
                                              ushort* __restrict__ feats) {
    const int x = blockIdx.x & 7, jb = blockIdx.x >> 3;
    const int w = threadIdx.x >> 6, lane = threadIdx.x & 63;
    const int start = (x * T2) >> 3;
    const int end = ((x + 1) * T2) >> 3;
    const int t = start + jb * 4 + w;
    if (t >= end) return;
    const int cls = t / CH, chunk = t % CH;
    const int br = cls >> 2, cg = cls & 3;
    const int half = lane >> 5, l32 = lane & 31;
    const int col = cg * 32 + l32;
    const ushort* hs = hs2all + (size_t)br * NN * 128 + col;
    const float* bias = (br == 0 ? b2a : br == 1 ? b2b : b2c);
    const float bcol = bias[col];
    const int n1 = min(chunk * 32 + 32, NN);

    for (int node = chunk * 32; node < n1; ++node) {
        const int g = br * NN + node;
        const ushort* csr = g_csr + seg3[g];
        const int len = cnt3[g] + 1;
        float acc = 0.f;
        int i = half;
        for (; i + 6 < len; i += 8) {
            int s0 = (i == 0) ? node : (int)csr[i - 1];
            int s1 = (int)csr[i + 1];
            int s2 = (int)csr[i + 3];
            int s3 = (int)csr[i + 5];
            float v0 = h2f(hs[(size_t)s0 * 128]);
            float v1 = h2f(hs[(size_t)s1 * 128]);
            float v2 = h2f(hs[(size_t)s2 * 128]);
            float v3 = h2f(hs[(size_t)s3 * 128]);
            acc += (v0 + v1) + (v2 + v3);
        }
        for (; i < len; i += 2) {
            int s = (i == 0) ? node : (int)csr[i - 1];
            acc += h2f(hs[(size_t)s * 128]);
        }
        acc += __shfl_xor(acc, 32);
        if (half == 0) {
            float f = dinv3[g] * acc + bcol;
            feats[(size_t)node * 384 + br * 128 + col] = f2h(f);
        }
    }
}

// ---------------- attention fusion (streaming, fp16 feats) ----------------

__global__ __launch_bounds__(256) void k_attn(const ushort* __restrict__ feats,
                                              const float* __restrict__ attn_w,
                                              const float* __restrict__ attn_b,
                                              float* __restrict__ out) {
    const int wid = threadIdx.x >> 6;
    const int lane = threadIdx.x & 63;
    const int node = blockIdx.x * 4 + wid;
    if (node >= NN) return;

    float2 w = *(const float2*)&attn_w[lane * 2];
    const ushort* f = feats + (size_t)node * 384;
    ushort2 u0 = *(const ushort2*)&f[0 * 128 + lane * 2];
    ushort2 u1 = *(const ushort2*)&f[1 * 128 + lane * 2];
    ushort2 u2 = *(const ushort2*)&f[2 * 128 + lane * 2];
    float f0x = h2f(u0.x), f0y = h2f(u0.y);
    float f1x = h2f(u1.x), f1y = h2f(u1.y);
    float f2x = h2f(u2.x), f2y = h2f(u2.y);

    float s0 = f0x * w.x + f0y * w.y;
    float s1 = f1x * w.x + f1y * w.y;
    float s2 = f2x * w.x + f2y * w.y;
#pragma unroll
    for (int m = 32; m >= 1; m >>= 1) {
        s0 += __shfl_xor(s0, m);
        s1 += __shfl_xor(s1, m);
        s2 += __shfl_xor(s2, m);
    }
    float bb = attn_b[0];
    s0 += bb; s1 += bb; s2 += bb;
    float mx = fmaxf(s0, fmaxf(s1, s2));
    float e0 = expf(s0 - mx), e1 = expf(s1 - mx), e2 = expf(s2 - mx);
    float inv = 1.f / (e0 + e1 + e2);
    e0 *= inv; e1 *= inv; e2 *= inv;

    float2 o;
    o.x = f0x * e0 + f1x * e1 + f2x * e2;
    o.y = f0y * e0 + f1y * e1 + f2y * e2;
    *(float2*)&out[(size_t)node * 128 + lane * 2] = o;
}

// ---------------- launch ----------------

extern "C" void kernel_launch(void* const* d_in, const int* in_sizes, int n_in,
                              void* d_out, int out_size, void* d_ws, size_t ws_size,
                              hipStream_t stream) {
    const float* x = (const float*)d_in[0];
    const int* e0 = (const int*)d_in[1];
    const int* e1 = (const int*)d_in[2];
    const int* e2 = (const int*)d_in[3];
    const float* attn_w = (const float*)d_in[16];
    const float* attn_b = (const float*)d_in[17];

    char* ws = (char*)d_ws;
    size_t off = 0;
    auto alloc = [&](size_t bytes) -> void* {
        void* p = ws + off;
        off += (bytes + 255) & ~(size_t)255;
        return p;
    };

    int* g_cur      = (int*)alloc(3 * BINS * 4);                 // zeroed
    int* seg3       = (int*)alloc((size_t)3 * NN * 4);
    int* cnt3       = (int*)alloc((size_t)3 * NN * 4);
    float* dinv3    = (float*)alloc((size_t)3 * NN * 4);
    ushort* g_csr   = (ushort*)alloc((size_t)3 * BINS * CAP * 2);  // 7.2 MB
    ushort* xp      = (ushort*)alloc((size_t)NN * 512 * 2);       // 51.2 MB
    ushort* hs2all  = xp;  // alias: xp dead after gemm1; hs2 (38.4 MB) fits
    ushort* hs16all = (ushort*)alloc((size_t)3 * NN * 256 * 2);   // 76.8 MB
    ushort* h1all   = (ushort*)alloc((size_t)3 * NN * 256 * 2);   // 76.8 MB
    unsigned* g_bins = (unsigned*)h1all;  // alias: g_bins dead before h1all written
    ushort* feats   = h1all;              // alias: h1all dead after gemm2
    ushort* BT1all  = (ushort*)alloc((size_t)3 * 256 * 768 * 2);
    ushort* BT2all  = (ushort*)alloc((size_t)3 * 128 * 256 * 2);

    const int WB = (NN + 3) / 4;  // 12500

    hipMemsetAsync(g_cur, 0, 3 * BINS * 4, stream);
    k_conv_x<<<WB, 256, 0, stream>>>(x, xp);
    k_conv_w1<<<768, 256, 0, stream>>>((const float*)d_in[4], (const float*)d_in[8],
                                       (const float*)d_in[12], BT1all);
    k_conv_w2<<<384, 256, 0, stream>>>((const float*)d_in[6], (const float*)d_in[10],
                                       (const float*)d_in[14], BT2all);

    k_bin<<<3 * P1B, 256, 0, stream>>>(e0, e1, e2, g_cur, g_bins);
    k_build<<<3 * BINS, 256, 0, stream>>>(g_bins, g_cur, g_csr, seg3, cnt3, dinv3);

    // layer 1: hs = dinv*(x @ W1) bf16x3 -> fp16; XCD-swizzled (shared A panels)
    k_gemm<128, 256, 256, 768, 512, false, true><<<1176, 512, 0, stream>>>(
        xp, 0, BT1all, 196608, dinv3, hs16all, (size_t)NN * 256);
    // class-swept column-split aggregation
    k_agg1<<<8 * ((TPX1 + 3) / 4), 256, 0, stream>>>(
        hs16all, seg3, cnt3, g_csr, dinv3,
        (const float*)d_in[5], (const float*)d_in[9], (const float*)d_in[13], h1all);

    // layer 2: hs2 = dinv*(h1 @ W2) fp16
    k_gemm<128, 128, 128, 256, 256, true, false><<<3 * 391, 256, 0, stream>>>(
        h1all, (size_t)NN * 256, BT2all, 32768, dinv3, hs2all, (size_t)NN * 128);

    // class-swept layer-2 aggregation -> feats (fp16), then streaming attention
    k_feat<<<8 * ((((T2 + 7) / 8) + 3) / 4), 256, 0, stream>>>(
        hs2all, seg3, cnt3, g_csr, dinv3,
        (const float*)d_in[7], (const float*)d_in[11], (const float*)d_in[15], feats);
    k_attn<<<WB, 256, 0, stream>>>(feats, attn_w, attn_b, (float*)d_out);
}

// Round 11
// 494.840 us; speedup vs baseline: 2.0770x; 2.0770x over previous
//
#include <hip/hip_runtime.h>

#define NN 50000
#define NE 800000
#define BINS 98      // bins of 512 nodes per branch
#define CAP 12288    // per-bin capacity (u32 records / ushort csr entries)
#define EPB 4096     // edges per phase-1 block
#define P1B ((NE + EPB - 1) / EPB)  // 196 blocks per branch

typedef __attribute__((ext_vector_type(8))) short short8;
typedef __attribute__((ext_vector_type(4))) float f32x4;
typedef __attribute__((ext_vector_type(8))) unsigned short ushort8v;
typedef __attribute__((ext_vector_type(4))) unsigned short ushort4v;
typedef _Float16 half8 __attribute__((ext_vector_type(8)));

__device__ __forceinline__ ushort f2bf(float f) {
    unsigned u = __float_as_uint(f);
    unsigned r = (u + 0x7fffu + ((u >> 16) & 1u)) >> 16;
    return (ushort)r;
}
__device__ __forceinline__ float bf2f(ushort h) {
    return __uint_as_float(((unsigned)h) << 16);
}
__device__ __forceinline__ ushort f2h(float f) {
    _Float16 h = (_Float16)f;
    return __builtin_bit_cast(ushort, h);
}
__device__ __forceinline__ float h2f(ushort u) {
    return (float)__builtin_bit_cast(_Float16, u);
}

// ---------------- phase 1: bin edges by dst>>9, coalesced line-exclusive flush ----

__global__ __launch_bounds__(256) void k_bin(const int* __restrict__ e0,
                                             const int* __restrict__ e1,
                                             const int* __restrict__ e2,
                                             int* __restrict__ g_cur,
                                             unsigned* __restrict__ g_bins) {
    const int br = blockIdx.x / P1B;
    const int cb = blockIdx.x % P1B;
    const int* ep = (br == 0 ? e0 : br == 1 ? e1 : e2);
    const int tid = threadIdx.x;
    const int e_base = cb * EPB;

    __shared__ int s_cnt[BINS];
    __shared__ int s_start[BINS];
    __shared__ int s_cur[BINS];
    __shared__ int s_gb[BINS];
    __shared__ unsigned s_stage[EPB];

    if (tid < BINS) s_cnt[tid] = 0;
    __syncthreads();

    int4 s4[4], d4[4];
    bool valid[4];
#pragma unroll
    for (int i = 0; i < 4; ++i) {
        int idx = e_base + i * 1024 + tid * 4;
        valid[i] = (idx < NE);  // idx%4==0, NE%4==0 -> full int4 valid
        if (valid[i]) {
            s4[i] = *(const int4*)&ep[idx];
            d4[i] = *(const int4*)&ep[NE + idx];
            atomicAdd(&s_cnt[d4[i].x >> 9], 1);
            atomicAdd(&s_cnt[d4[i].y >> 9], 1);
            atomicAdd(&s_cnt[d4[i].z >> 9], 1);
            atomicAdd(&s_cnt[d4[i].w >> 9], 1);
        }
    }
    __syncthreads();
    if (tid == 0) {
        int run = 0;
        for (int b = 0; b < BINS; ++b) {
            s_start[b] = run;
            run += s_cnt[b];
        }
    }
    __syncthreads();
    if (tid < BINS) {
        s_cur[tid] = s_start[tid];
        int c = s_cnt[tid];
        int pc = (c + 15) & ~15;  // 64B-aligned reservation
        s_gb[tid] = (c > 0) ? atomicAdd(&g_cur[br * BINS + tid], pc) : 0;
    }
    __syncthreads();

#pragma unroll
    for (int i = 0; i < 4; ++i) {
        if (valid[i]) {
            int ss[4] = {s4[i].x, s4[i].y, s4[i].z, s4[i].w};
            int dd[4] = {d4[i].x, d4[i].y, d4[i].z, d4[i].w};
#pragma unroll
            for (int q = 0; q < 4; ++q) {
                int bin = dd[q] >> 9;
                int pos = atomicAdd(&s_cur[bin], 1);
                s_stage[pos] = ((unsigned)(dd[q] & 511) << 16) | (unsigned)ss[q];
            }
        }
    }
    __syncthreads();

    for (int b = 0; b < BINS; ++b) {
        int c = s_cnt[b];
        if (c == 0) continue;
        int st = s_start[b];
        int gb = s_gb[b];
        int pc = (c + 15) & ~15;
        if (gb + pc > CAP) pc = (gb < CAP) ? (CAP - gb) : 0;  // overflow guard
        size_t obase = (size_t)(br * BINS + b) * CAP + gb;
        for (int j = tid; j < pc; j += 256)
            g_bins[obase + j] = (j < c) ? s_stage[st + j] : 0x80000000u;
    }
}

// ---------------- phase 2: per-bin CSR build with LDS atomics ----------------

__device__ __forceinline__ int wave_incl_scan(int v, int lane) {
#pragma unroll
    for (int d = 1; d < 64; d <<= 1) {
        int u = __shfl_up(v, d);
        if (lane >= d) v += u;
    }
    return v;
}

__global__ __launch_bounds__(256) void k_build(const unsigned* __restrict__ g_bins,
                                               const int* __restrict__ g_cur,
                                               ushort* __restrict__ g_csr,
                                               int* __restrict__ seg3,
                                               int* __restrict__ cnt3,
                                               float* __restrict__ dinv3) {
    const int bid = blockIdx.x;  // branch*BINS + bin
    const int br = bid / BINS;
    const int b2 = bid % BINS;
    const size_t base = (size_t)bid * CAP;
    const int node0 = b2 << 9;
    const int tid = threadIdx.x;

    __shared__ int s_cnt[512];
    __shared__ int s_off[512];
    __shared__ int s_wsum[4];

    s_cnt[tid] = 0;
    s_cnt[tid + 256] = 0;
    __syncthreads();

    const int total = min(g_cur[bid], CAP);
    for (int j = tid; j < total; j += 256) {
        unsigned p = g_bins[base + j];
        if (!(p & 0x80000000u)) atomicAdd(&s_cnt[(p >> 16) & 0x1FF], 1);
    }
    __syncthreads();

    // exclusive scan of 512 counts (pairs per thread + wave scan)
    const int lane = tid & 63, w = tid >> 6;
    int c0 = s_cnt[2 * tid], c1 = s_cnt[2 * tid + 1];
    int c2 = c0 + c1;
    int incl = wave_incl_scan(c2, lane);
    if (lane == 63) s_wsum[w] = incl;
    __syncthreads();
    int wpre = 0;
    for (int i = 0; i < w; ++i) wpre += s_wsum[i];
    int ex = wpre + incl - c2;
    s_off[2 * tid] = ex;
    s_off[2 * tid + 1] = ex + c0;

#pragma unroll
    for (int q = 0; q < 2; ++q) {
        int local = 2 * tid + q;
        int node = node0 + local;
        if (node < NN) {
            int g = br * NN + node;
            int c = (q == 0) ? c0 : c1;
            seg3[g] = (int)base + s_off[local];
            cnt3[g] = c;
            dinv3[g] = rsqrtf((float)(c + 1));
        }
    }
    __syncthreads();
    // cursors
    s_cnt[2 * tid] = s_off[2 * tid];
    s_cnt[2 * tid + 1] = s_off[2 * tid + 1];
    __syncthreads();

    for (int j = tid; j < total; j += 256) {
        unsigned p = g_bins[base + j];
        if (!(p & 0x80000000u)) {
            int loc = (p >> 16) & 0x1FF;
            int pos = atomicAdd(&s_cnt[loc], 1);
            g_csr[base + pos] = (ushort)(p & 0xFFFFu);
        }
    }
}

// ---------------- conversions ----------------

__global__ __launch_bounds__(256) void k_conv_x(const float* __restrict__ x,
                                                ushort* __restrict__ xp) {
    const int wid = threadIdx.x >> 6, lane = threadIdx.x & 63;
    const int row = blockIdx.x * 4 + wid;
    if (row >= NN) return;
    float4 v = *(const float4*)&x[(size_t)row * 256 + lane * 4];
    ushort4 hi, lo;
    hi.x = f2bf(v.x); lo.x = f2bf(v.x - bf2f(hi.x));
    hi.y = f2bf(v.y); lo.y = f2bf(v.y - bf2f(hi.y));
    hi.z = f2bf(v.z); lo.z = f2bf(v.z - bf2f(hi.z));
    hi.w = f2bf(v.w); lo.w = f2bf(v.w - bf2f(hi.w));
    *(ushort4*)&xp[(size_t)row * 512 + lane * 4] = hi;
    *(ushort4*)&xp[(size_t)row * 512 + 256 + lane * 4] = lo;
}

__global__ __launch_bounds__(256) void k_conv_w1(const float* __restrict__ w0,
                                                 const float* __restrict__ w1,
                                                 const float* __restrict__ w2,
                                                 ushort* __restrict__ BT1all) {
    int idx = blockIdx.x * 256 + threadIdx.x;  // 3 * 65536
    int b = idx >> 16, r = idx & 65535;
    int k = r >> 8, n = r & 255;
    const float* W = (b == 0 ? w0 : b == 1 ? w1 : w2);
    float w = W[r];
    ushort hi = f2bf(w);
    ushort lo = f2bf(w - bf2f(hi));
    ushort* row = BT1all + (size_t)b * 196608 + (size_t)n * 768;
    row[k] = hi;
    row[256 + k] = hi;
    row[512 + k] = lo;
}

__global__ __launch_bounds__(256) void k_conv_w2(const float* __restrict__ w0,
                                                 const float* __restrict__ w1,
                                                 const float* __restrict__ w2,
                                                 ushort* __restrict__ BT2all) {
    int idx = blockIdx.x * 256 + threadIdx.x;  // 3 * 32768
    int b = idx >> 15, r = idx & 32767;
    int k = r >> 7, n = r & 127;
    const float* W = (b == 0 ? w0 : b == 1 ? w1 : w2);
    BT2all[(size_t)b * 32768 + (size_t)n * 256 + k] = f2h(W[r]);
}

// ---------------- MFMA GEMM1: 2-phase double-buffered pipeline, XCD-swizzled ----

template <int BM, int BN, int N, int KK, int AK, bool HALF, bool XSWZ>
__global__ __launch_bounds__((BM / 64) * (BN / 64) * 64) void k_gemm(
    const ushort* __restrict__ A, size_t aBatch,
    const ushort* __restrict__ BTall, int btBatch,
    const float* __restrict__ dinv3, ushort* __restrict__ Call, size_t cBatch) {
    constexpr int WGN = BN / 64, NW = (BM / 64) * WGN;
    constexpr int BK = 32;
    constexpr int MT = (NN + BM - 1) / BM, NT = N / BN, GB = MT * NT;
    constexpr int NSTEP = KK / BK;
    __shared__ ushort sA[2][BM * BK];
    __shared__ ushort sB[2][BN * BK];
    int kb, bid;
    if constexpr (XSWZ) {
        int q = blockIdx.x >> 3, r = blockIdx.x & 7;
        bid = (q / 3) * 8 + r;   // M-tile
        kb = q % 3;              // branch
        if (bid >= GB) return;
    } else {
        kb = blockIdx.x / GB;
        bid = blockIdx.x % GB;
    }
    const ushort* Ab = A + (size_t)kb * aBatch;
    const ushort* BT = BTall + (size_t)kb * btBatch;
    const float* dinv = dinv3 + (size_t)kb * NN;
    ushort* C = Call + (size_t)kb * cBatch;
    const int t = threadIdx.x, lane = t & 63, wid = t >> 6;
    const int wm = (wid / WGN) * 64, wn = (wid % WGN) * 64;
    const int bm = (bid / NT) * BM;
    const int bn = (bid % NT) * BN;

    f32x4 zero = {0.f, 0.f, 0.f, 0.f};
    f32x4 acc[4][4];
#pragma unroll
    for (int m = 0; m < 4; ++m)
#pragma unroll
        for (int n = 0; n < 4; ++n) acc[m][n] = zero;

    constexpr int A_ISS = (BM * BK * 2) / (NW * 1024);
    constexpr int B_ISS = (BN * BK * 2) / (NW * 1024);

    auto stage = [&](int buf, int kt) {
        const int akt = (kt >= AK) ? kt - AK : kt;  // A hi-block reuse
#pragma unroll
        for (int i = 0; i < A_ISS; ++i) {
            int off = (wid + i * NW) << 10;
            int la = off + lane * 16;
            int row = la >> 6;
            int slot = (la >> 4) & 3;
            int scol = (slot ^ (row & 3)) << 4;
            int grow = bm + row;
            if (grow > NN - 1) grow = NN - 1;
            const char* ga = (const char*)Ab + (size_t)grow * (AK * 2) + akt * 2 + scol;
            __builtin_amdgcn_global_load_lds(
                (__attribute__((address_space(1))) const void*)ga,
                (__attribute__((address_space(3))) void*)((char*)sA[buf] + off), 16, 0, 0);
        }
#pragma unroll
        for (int i = 0; i < B_ISS; ++i) {
            int off = (wid + i * NW) << 10;
            int la = off + lane * 16;
            int row = la >> 6;
            int slot = (la >> 4) & 3;
            int scol = (slot ^ (row & 3)) << 4;
            const char* ga = (const char*)BT + (size_t)(bn + row) * (KK * 2) + kt * 2 + scol;
            __builtin_amdgcn_global_load_lds(
                (__attribute__((address_space(1))) const void*)ga,
                (__attribute__((address_space(3))) void*)((char*)sB[buf] + off), 16, 0, 0);
        }
    };

    stage(0, 0);
    __syncthreads();  // drain prologue loads

    int cur = 0;
    for (int ts = 0; ts < NSTEP; ++ts) {
        if (ts + 1 < NSTEP) stage(cur ^ 1, (ts + 1) * BK);  // overlap with MFMA

        const int s = lane >> 4;
        const int r0 = lane & 15;
        short8 af[4], bf[4];
#pragma unroll
        for (int m = 0; m < 4; ++m) {
            int row = wm + m * 16 + r0;
            af[m] = *(const short8*)((const char*)sA[cur] + row * 64 + ((s ^ (row & 3)) << 4));
        }
#pragma unroll
        for (int n = 0; n < 4; ++n) {
            int row = wn + n * 16 + r0;
            bf[n] = *(const short8*)((const char*)sB[cur] + row * 64 + ((s ^ (row & 3)) << 4));
        }
#pragma unroll
        for (int m = 0; m < 4; ++m)
#pragma unroll
            for (int n = 0; n < 4; ++n) {
                if constexpr (HALF)
                    acc[m][n] = __builtin_amdgcn_mfma_f32_16x16x32_f16(
                        __builtin_bit_cast(half8, af[m]), __builtin_bit_cast(half8, bf[n]),
                        acc[m][n], 0, 0, 0);
                else
                    acc[m][n] = __builtin_amdgcn_mfma_f32_16x16x32_bf16(af[m], bf[n],
                                                                        acc[m][n], 0, 0, 0);
            }
        __syncthreads();  // drains vmcnt(0): next tile staged & visible
        cur ^= 1;
    }

    const int cr0 = (lane >> 4) * 4;
    const int cc = lane & 15;
#pragma unroll
    for (int m = 0; m < 4; ++m) {
#pragma unroll
        for (int r = 0; r < 4; ++r) {
            int row = bm + wm + m * 16 + cr0 + r;
            if (row < NN) {
                float dv = dinv[row];
#pragma unroll
                for (int n = 0; n < 4; ++n)
                    C[(size_t)row * N + bn + wn + n * 16 + cc] = f2h(acc[m][n][r] * dv);
            }
        }
    }
}

// ---------------- FUSED layer-1 aggregation + layer-2 GEMM ----------------
// Block = 16 dest nodes of one branch, 256 threads (4 waves).
// Phase A: gather h1[16][256] fp16 into LDS (XOR-swizzled 16B slots) -- h1
// never touches HBM (saves 77MB write + 77MB re-read vs separate gemm2).
// Phase B: hs2[16][128] = dinv*(h1 @ W2) via MFMA; B-frags register-loaded
// from L2-hot 64KB W2. MFMA rides the matrix pipe under the fabric-bound
// gather of co-resident blocks.

__global__ __launch_bounds__(256) void k_agg1g2(
    const ushort* __restrict__ hs16all, const int* __restrict__ seg3,
    const int* __restrict__ cnt3, const ushort* __restrict__ g_csr,
    const float* __restrict__ dinv3,
    const float* __restrict__ b1a, const float* __restrict__ b1b,
    const float* __restrict__ b1c,
    const ushort* __restrict__ BT2all, ushort* __restrict__ hs2all) {
    const int br = blockIdx.x / 3125;   // NN/16 = 3125 exactly
    const int blk = blockIdx.x % 3125;
    const int node0 = blk * 16;
    const int w = threadIdx.x >> 6, lane = threadIdx.x & 63;
    const int half = lane >> 5, l32 = lane & 31;

    __shared__ ushort h1s[16 * 256];  // 8 KB

    const ushort* hs = hs16all + (size_t)br * NN * 256;
    const float* bias = (br == 0 ? b1a : br == 1 ? b1b : b1c);
    const size_t colb = (size_t)l32 * 8;

    // Phase A: wave w gathers local rows w*4 .. w*4+3
#pragma unroll 1
    for (int q = 0; q < 4; ++q) {
        const int r = w * 4 + q;
        const int node = node0 + r;
        const int g = br * NN + node;
        const ushort* csr = g_csr + seg3[g];
        const int len = cnt3[g] + 1;

        float acc[8] = {0.f, 0.f, 0.f, 0.f, 0.f, 0.f, 0.f, 0.f};
        int i = half;
        for (; i + 6 < len; i += 8) {
            int s0 = (i == 0) ? node : (int)csr[i - 1];
            int s1 = (int)csr[i + 1];
            int s2 = (int)csr[i + 3];
            int s3 = (int)csr[i + 5];
            ushort8v v0 = *(const ushort8v*)&hs[(size_t)s0 * 256 + colb];
            ushort8v v1 = *(const ushort8v*)&hs[(size_t)s1 * 256 + colb];
            ushort8v v2 = *(const ushort8v*)&hs[(size_t)s2 * 256 + colb];
            ushort8v v3 = *(const ushort8v*)&hs[(size_t)s3 * 256 + colb];
#pragma unroll
            for (int j = 0; j < 8; ++j)
                acc[j] += (h2f(v0[j]) + h2f(v1[j])) + (h2f(v2[j]) + h2f(v3[j]));
        }
        for (; i < len; i += 2) {
            int s = (i == 0) ? node : (int)csr[i - 1];
            ushort8v v = *(const ushort8v*)&hs[(size_t)s * 256 + colb];
#pragma unroll
            for (int j = 0; j < 8; ++j) acc[j] += h2f(v[j]);
        }
#pragma unroll
        for (int j = 0; j < 8; ++j) acc[j] += __shfl_xor(acc[j], 32);

        if (half == 0) {
            const float di = dinv3[g];
            ushort8v o;
#pragma unroll
            for (int j = 0; j < 8; ++j) {
                float rr = fmaxf(di * acc[j] + bias[l32 * 8 + j], 0.f);
                o[j] = f2h(rr);
            }
            // swizzled slot: (l32 ^ (r&7)) within row r
            *(ushort8v*)((char*)h1s + r * 512 + ((l32 ^ (r & 7)) << 4)) = o;
        }
    }
    __syncthreads();

    // Phase B: wave w owns output cols wn = w*32 (two 16-col MFMA tiles)
    const int r0 = lane & 15, s = lane >> 4;
    const int wn = w * 32;
    const ushort* BT2 = BT2all + (size_t)br * 32768;
    f32x4 zero = {0.f, 0.f, 0.f, 0.f};
    f32x4 acc0 = zero, acc1 = zero;
#pragma unroll
    for (int ks = 0; ks < 8; ++ks) {
        const int kt = ks * 32;
        const int slot = ((kt >> 3) + s) ^ (r0 & 7);
        short8 a = *(const short8*)((const char*)h1s + r0 * 512 + (slot << 4));
        short8 b0 = *(const short8*)&BT2[(size_t)(wn + r0) * 256 + kt + s * 8];
        short8 b1 = *(const short8*)&BT2[(size_t)(wn + 16 + r0) * 256 + kt + s * 8];
        acc0 = __builtin_amdgcn_mfma_f32_16x16x32_f16(
            __builtin_bit_cast(half8, a), __builtin_bit_cast(half8, b0), acc0, 0, 0, 0);
        acc1 = __builtin_amdgcn_mfma_f32_16x16x32_f16(
            __builtin_bit_cast(half8, a), __builtin_bit_cast(half8, b1), acc1, 0, 0, 0);
    }

    // C write: row = (lane>>4)*4 + reg, col = lane&15
    const int cc = lane & 15;
    const int rbase = (lane >> 4) * 4;
#pragma unroll
    for (int rg = 0; rg < 4; ++rg) {
        const int node = node0 + rbase + rg;
        const float dv = dinv3[br * NN + node];
        ushort* orow = hs2all + ((size_t)br * NN + node) * 128;
        orow[wn + cc] = f2h(acc0[rg] * dv);
        orow[wn + 16 + cc] = f2h(acc1[rg] * dv);
    }
}

// ---------------- fused layer-2 aggregation (x3) + attention ----------------

__global__ __launch_bounds__(256) void k_final(const ushort* __restrict__ hs2all,
                                               const int* __restrict__ seg3,
                                               const int* __restrict__ cnt3,
                                               const ushort* __restrict__ g_csr,
                                               const float* __restrict__ dinv3,
                                               const float* __restrict__ b2a,
                                               const float* __restrict__ b2b,
                                               const float* __restrict__ b2c,
                                               const float* __restrict__ attn_w,
                                               const float* __restrict__ attn_b,
                                               float* __restrict__ out) {
    const int wid = threadIdx.x >> 6;
    const int lane = threadIdx.x & 63;
    const int node = blockIdx.x * 4 + wid;
    if (node >= NN) return;
    const int half = lane >> 5, l32 = lane & 31;
    const size_t colb = (size_t)l32 * 4;

    float f[3][4];
#pragma unroll
    for (int b = 0; b < 3; ++b) {
        const int g = b * NN + node;
        const ushort* hs = hs2all + (size_t)b * NN * 128;
        const ushort* csr = g_csr + seg3[g];
        const int len = cnt3[g] + 1;
        float acc[4] = {0.f, 0.f, 0.f, 0.f};
        int i = half;
        for (; i + 6 < len; i += 8) {
            int s0 = (i == 0) ? node : (int)csr[i - 1];
            int s1 = (int)csr[i + 1];
            int s2 = (int)csr[i + 3];
            int s3 = (int)csr[i + 5];
            ushort4v v0 = *(const ushort4v*)&hs[(size_t)s0 * 128 + colb];
            ushort4v v1 = *(const ushort4v*)&hs[(size_t)s1 * 128 + colb];
            ushort4v v2 = *(const ushort4v*)&hs[(size_t)s2 * 128 + colb];
            ushort4v v3 = *(const ushort4v*)&hs[(size_t)s3 * 128 + colb];
#pragma unroll
            for (int j = 0; j < 4; ++j)
                acc[j] += (h2f(v0[j]) + h2f(v1[j])) + (h2f(v2[j]) + h2f(v3[j]));
        }
        for (; i < len; i += 2) {
            int s = (i == 0) ? node : (int)csr[i - 1];
            ushort4v v = *(const ushort4v*)&hs[(size_t)s * 128 + colb];
#pragma unroll
            for (int j = 0; j < 4; ++j) acc[j] += h2f(v[j]);
        }
#pragma unroll
        for (int j = 0; j < 4; ++j) acc[j] += __shfl_xor(acc[j], 32);
        const float* bias = (b == 0 ? b2a : b == 1 ? b2b : b2c);
        const float di = dinv3[g];
#pragma unroll
        for (int j = 0; j < 4; ++j) f[b][j] = di * acc[j] + bias[l32 * 4 + j];
    }

    float4 w = *(const float4*)&attn_w[l32 * 4];
    float s0 = f[0][0] * w.x + f[0][1] * w.y + f[0][2] * w.z + f[0][3] * w.w;
    float s1 = f[1][0] * w.x + f[1][1] * w.y + f[1][2] * w.z + f[1][3] * w.w;
    float s2 = f[2][0] * w.x + f[2][1] * w.y + f[2][2] * w.z + f[2][3] * w.w;
#pragma unroll
    for (int m = 16; m >= 1; m >>= 1) {
        s0 += __shfl_xor(s0, m);
        s1 += __shfl_xor(s1, m);
        s2 += __shfl_xor(s2, m);
    }
    float bb = attn_b[0];
    s0 += bb; s1 += bb; s2 += bb;
    float mx = fmaxf(s0, fmaxf(s1, s2));
    float e0 = expf(s0 - mx), e1 = expf(s1 - mx), e2 = expf(s2 - mx);
    float inv = 1.f / (e0 + e1 + e2);
    e0 *= inv; e1 *= inv; e2 *= inv;

    if (half == 0) {
        float4 o;
        o.x = f[0][0] * e0 + f[1][0] * e1 + f[2][0] * e2;
        o.y = f[0][1] * e0 + f[1][1] * e1 + f[2][1] * e2;
        o.z = f[0][2] * e0 + f[1][2] * e1 + f[2][2] * e2;
        o.w = f[0][3] * e0 + f[1][3] * e1 + f[2][3] * e2;
        *(float4*)&out[(size_t)node * 128 + colb] = o;
    }
}

// ---------------- launch ----------------

extern "C" void kernel_launch(void* const* d_in, const int* in_sizes, int n_in,
                              void* d_out, int out_size, void* d_ws, size_t ws_size,
                              hipStream_t stream) {
    const float* x = (const float*)d_in[0];
    const int* e0 = (const int*)d_in[1];
    const int* e1 = (const int*)d_in[2];
    const int* e2 = (const int*)d_in[3];
    const float* attn_w = (const float*)d_in[16];
    const float* attn_b = (const float*)d_in[17];

    char* ws = (char*)d_ws;
    size_t off = 0;
    auto alloc = [&](size_t bytes) -> void* {
        void* p = ws + off;
        off += (bytes + 255) & ~(size_t)255;
        return p;
    };

    int* g_cur      = (int*)alloc(3 * BINS * 4);                   // zeroed
    int* seg3       = (int*)alloc((size_t)3 * NN * 4);
    int* cnt3       = (int*)alloc((size_t)3 * NN * 4);
    float* dinv3    = (float*)alloc((size_t)3 * NN * 4);
    ushort* g_csr   = (ushort*)alloc((size_t)3 * BINS * CAP * 2);  // 7.2 MB
    unsigned* g_bins = (unsigned*)alloc((size_t)3 * BINS * CAP * 4);  // 14.4 MB
    ushort* xp      = (ushort*)alloc((size_t)NN * 512 * 2);        // 51.2 MB
    ushort* hs2all  = xp;  // alias: xp dead after gemm1; hs2 (38.4 MB) fits
    ushort* hs16all = (ushort*)alloc((size_t)3 * NN * 256 * 2);    // 76.8 MB
    ushort* BT1all  = (ushort*)alloc((size_t)3 * 256 * 768 * 2);
    ushort* BT2all  = (ushort*)alloc((size_t)3 * 128 * 256 * 2);

    const int WB = (NN + 3) / 4;  // 12500

    hipMemsetAsync(g_cur, 0, 3 * BINS * 4, stream);
    k_conv_x<<<WB, 256, 0, stream>>>(x, xp);
    k_conv_w1<<<768, 256, 0, stream>>>((const float*)d_in[4], (const float*)d_in[8],
                                       (const float*)d_in[12], BT1all);
    k_conv_w2<<<384, 256, 0, stream>>>((const float*)d_in[6], (const float*)d_in[10],
                                       (const float*)d_in[14], BT2all);

    k_bin<<<3 * P1B, 256, 0, stream>>>(e0, e1, e2, g_cur, g_bins);
    k_build<<<3 * BINS, 256, 0, stream>>>(g_bins, g_cur, g_csr, seg3, cnt3, dinv3);

    // layer 1: hs = dinv*(x @ W1) bf16x3 -> fp16; XCD-swizzled (shared A panels)
    k_gemm<128, 256, 256, 768, 512, false, true><<<1176, 512, 0, stream>>>(
        xp, 0, BT1all, 196608, dinv3, hs16all, (size_t)NN * 256);

    // fused: agg1 (gather+relu, h1 in LDS only) + gemm2 -> hs2 fp16
    k_agg1g2<<<3 * 3125, 256, 0, stream>>>(
        hs16all, seg3, cnt3, g_csr, dinv3,
        (const float*)d_in[5], (const float*)d_in[9], (const float*)d_in[13],
        BT2all, hs2all);

    // fused layer-2 aggregation + attention
    k_final<<<WB, 256, 0, stream>>>(hs2all, seg3, cnt3, g_csr, dinv3,
                                    (const float*)d_in[7], (const float*)d_in[11],
                                    (const float*)d_in[15], attn_w, attn_b,
                                    (float*)d_out);
}